// Round 7
// baseline (43.112 us; speedup 1.0000x reference)
//
#include <hip/hip_runtime.h>
#include <math.h>

#define EMBED   64
#define BATCH   2048
#define NTOT    4096
#define NITEMS  10000
#define TILE    64
#define NT      64               // NTOT/TILE
#define NTILES  2080             // NT*(NT+1)/2, == 8*260
#define SROW    66               // bf16 LDS row stride: 33 dwords == 1 mod 32
#define NB_BPP  128              // 128 blocks x 16 waves = 2048 batch elems

typedef __attribute__((ext_vector_type(8))) short short8;
typedef __attribute__((ext_vector_type(4))) float f32x4;

__device__ __forceinline__ unsigned short f2bf(float f) {   // RNE fp32->bf16
    unsigned u = __float_as_uint(f);
    return (unsigned short)((u + 0x7FFFu + ((u >> 16) & 1u)) >> 16);
}

// block 0: counting sort of (id, orig) keys; blocks 1..128: bpp partials.
__global__ __launch_bounds__(1024) void combo_kernel(
    const int* __restrict__ user_id, const int* __restrict__ pos_id,
    const int* __restrict__ neg_id, const float* __restrict__ user_table,
    const float* __restrict__ item_table,
    int* __restrict__ sorted_id, int* __restrict__ sorted_orig,
    float* __restrict__ bpp_part)
{
    int blk = blockIdx.x, t = threadIdx.x;
    if (blk == 0) {
        __shared__ int hist[NITEMS];
        __shared__ unsigned key2[NTOT];
        __shared__ int wtot[16];
        for (int i = t; i < NITEMS; i += 1024) hist[i] = 0;
        __syncthreads();
        for (int i = t; i < NTOT; i += 1024) {
            int id = (i < BATCH) ? pos_id[i] : neg_id[i - BATCH];
            atomicAdd(&hist[id], 1);
        }
        __syncthreads();
        // exclusive scan over 10000 bins: 10 bins/thread, wave-shfl scan
        int b0 = t * 10, bend = min(b0 + 10, NITEMS);
        int s = 0;
        for (int b = b0; b < bend; ++b) s += hist[b];
        int lane = t & 63, wid = t >> 6;
        int v = s;
        #pragma unroll
        for (int off = 1; off < 64; off <<= 1) {
            int y = __shfl_up(v, off, 64);
            if (lane >= off) v += y;
        }
        if (lane == 63) wtot[wid] = v;
        __syncthreads();
        if (t == 0) {
            int run = 0;
            #pragma unroll
            for (int w = 0; w < 16; ++w) { int c = wtot[w]; wtot[w] = run; run += c; }
        }
        __syncthreads();
        int running = v - s + wtot[wid];   // exclusive prefix for this thread's bins
        for (int b = b0; b < bend; ++b) { int c = hist[b]; hist[b] = running; running += c; }
        __syncthreads();
        // scatter (atomic within bin), canonicalize equal-id runs by orig pos
        for (int i = t; i < NTOT; i += 1024) {
            int id = (i < BATCH) ? pos_id[i] : neg_id[i - BATCH];
            int pos = atomicAdd(&hist[id], 1);
            key2[pos] = ((unsigned)id << 12) | (unsigned)i;
        }
        __syncthreads();
        for (int p = 0; p < 12; ++p) {          // odd-even; run length <=12 whp
            int start = p & 1;
            for (int q = t; q < NTOT / 2; q += 1024) {
                int a = 2 * q + start;
                if (a + 1 < NTOT) {
                    unsigned x = key2[a], y = key2[a + 1];
                    if (x > y) { key2[a] = y; key2[a + 1] = x; }
                }
            }
            __syncthreads();
        }
        for (int i = t; i < NTOT; i += 1024) {
            sorted_id[i]   = (int)(key2[i] >> 12);
            sorted_orig[i] = (int)(key2[i] & 4095u);
        }
    } else {
        // bpp: 16 waves, one batch element per wave
        int b    = (blk - 1) * 16 + (t >> 6);
        int lane = t & 63;
        float u = user_table[user_id[b] * EMBED + lane];
        float p = item_table[pos_id[b]  * EMBED + lane];
        float n = item_table[neg_id[b]  * EMBED + lane];
        float dp = u * p, dn = u * n;
        #pragma unroll
        for (int off = 32; off; off >>= 1) {
            dp += __shfl_xor(dp, off, 64);
            dn += __shfl_xor(dn, off, 64);
        }
        float x = dn - dp;
        float sp = fmaxf(x, 0.f) + log1pf(expf(-fabsf(x)));
        __shared__ float red[16];
        if (lane == 0) red[t >> 6] = sp;
        __syncthreads();
        if (t == 0) {
            float ssum = 0.f;
            #pragma unroll
            for (int w = 0; w < 16; ++w) ssum += red[w];
            bpp_part[blk - 1] = ssum;
        }
    }
}

// One block per upper-tri 64x64 tile: MFMA dot tile + masked D-gather.
// Row norms computed in-register from the fp32 staging values.
// Gathers issued BEFORE the MFMA section so L3 latency hides under it.
__global__ __launch_bounds__(256, 6) void reg_kernel(
    const float* __restrict__ item_table,
    const int* __restrict__ sorted_id, const int* __restrict__ sorted_orig,
    const float* __restrict__ D,
    float* __restrict__ partials)
{
    __shared__ unsigned short sa[TILE][SROW];
    __shared__ unsigned short sb[TILE][SROW];
    __shared__ float sqi[TILE], sqj[TILE];
    __shared__ int idi[TILE], idj[TILE], idiN[TILE], idjN[TILE], ogi[TILE], ogj[TILE];
    __shared__ float wsum[4];

    // XCD-aware swizzle: 2080 = 8 * 260 exactly -> bijective
    int bs = blockIdx.x;
    int b  = (bs & 7) * (NTILES / 8) + (bs >> 3);
    int tI = 0, rem = b;
    while (rem >= NT - tI) { rem -= NT - tI; ++tI; }
    int tJ = tI + rem;

    int t = threadIdx.x;
    int r = t >> 2, c = t & 3;    // staging: row 0..63, 16-float chunk 0..3

    if (t < TILE) {
        int g = tI * TILE + t, id = sorted_id[g];
        idi[t] = id; idiN[t] = id * NITEMS; ogi[t] = sorted_orig[g];
    } else if (t < 2 * TILE) {
        int rr = t - TILE, g = tJ * TILE + rr, id = sorted_id[g];
        idj[rr] = id; idjN[rr] = id * NITEMS; ogj[rr] = sorted_orig[g];
    }

    {   // stage both 64x64 fp32 slabs, convert to bf16, fold norm partials
        int idI = sorted_id[tI * TILE + r];
        int idJ = sorted_id[tJ * TILE + r];
        const float4* srcI = (const float4*)&item_table[idI * EMBED + c * 16];
        const float4* srcJ = (const float4*)&item_table[idJ * EMBED + c * 16];
        float npI = 0.f, npJ = 0.f;
        #pragma unroll
        for (int k = 0; k < 4; ++k) {
            float4 aI = srcI[k];
            float4 aJ = srcJ[k];
            npI = fmaf(aI.x, aI.x, fmaf(aI.y, aI.y, fmaf(aI.z, aI.z, fmaf(aI.w, aI.w, npI))));
            npJ = fmaf(aJ.x, aJ.x, fmaf(aJ.y, aJ.y, fmaf(aJ.z, aJ.z, fmaf(aJ.w, aJ.w, npJ))));
            ushort4 sI = { f2bf(aI.x), f2bf(aI.y), f2bf(aI.z), f2bf(aI.w) };
            ushort4 sJ = { f2bf(aJ.x), f2bf(aJ.y), f2bf(aJ.z), f2bf(aJ.w) };
            *(ushort4*)&sa[r][c * 16 + k * 4] = sI;
            *(ushort4*)&sb[r][c * 16 + k * 4] = sJ;
        }
        // reduce the 4 chunk-threads (adjacent lanes) of each row
        npI += __shfl_xor(npI, 1, 64); npI += __shfl_xor(npI, 2, 64);
        npJ += __shfl_xor(npJ, 1, 64); npJ += __shfl_xor(npJ, 2, 64);
        if (c == 0) { sqi[r] = npI; sqj[r] = npJ; }
    }
    __syncthreads();

    int w = t >> 6, l = t & 63;
    int i_base = w * 16 + (l >> 4) * 4;

    // Phase 1: all 16 gather addresses (independent of MFMA), loads up-front.
    int addr[16];
    #pragma unroll
    for (int cb = 0; cb < 4; ++cb) {
        int j_loc = cb * 16 + (l & 15);
        int idb = idj[j_loc], idbN = idjN[j_loc], ob = ogj[j_loc];
        #pragma unroll
        for (int rr = 0; rr < 4; ++rr) {
            int i_loc = i_base + rr;
            bool fwd = ogi[i_loc] < ob;
            addr[cb * 4 + rr] = fwd ? (idiN[i_loc] + idb) : (idbN + idi[i_loc]);
        }
    }
    float dg[16];
    #pragma unroll
    for (int k = 0; k < 16; ++k) dg[k] = D[addr[k]];

    // Phase 2: MFMA dot tile. Wave w owns rows [w*16,w*16+16) x 64 cols.
    int arow = w * 16 + (l & 15);
    int kb   = (l >> 4) * 8;
    f32x4 acc[4];
    #pragma unroll
    for (int cb = 0; cb < 4; ++cb) acc[cb] = (f32x4){0.f, 0.f, 0.f, 0.f};
    #pragma unroll
    for (int s = 0; s < 2; ++s) {
        short8 af = *(const short8*)&sa[arow][s * 32 + kb];
        #pragma unroll
        for (int cb = 0; cb < 4; ++cb) {
            short8 bf = *(const short8*)&sb[cb * 16 + (l & 15)][s * 32 + kb];
            acc[cb] = __builtin_amdgcn_mfma_f32_16x16x32_bf16(af, bf, acc[cb], 0, 0, 0);
        }
    }

    // Phase 3: distances, mask, fma with gathered D.
    // C/D map col=lane&15, row=(lane>>4)*4+reg (m89-verified).
    bool offdiag = (tI != tJ);   // wave-uniform
    float accsum = 0.f;
    #pragma unroll
    for (int cb = 0; cb < 4; ++cb) {
        int j_loc = cb * 16 + (l & 15);
        float sqb = sqj[j_loc];
        #pragma unroll
        for (int rr = 0; rr < 4; ++rr) {
            int i_loc = i_base + rr;
            float d2 = sqi[i_loc] + sqb - 2.f * acc[cb][rr];
            bool m = (d2 > 0.f) && (offdiag || (i_loc < j_loc));
            accsum = m ? fmaf(dg[cb * 4 + rr], sqrtf(d2), accsum) : accsum;
        }
    }

    // wave shfl-reduce, then block sum via 4-entry LDS
    #pragma unroll
    for (int off = 32; off; off >>= 1) accsum += __shfl_xor(accsum, off, 64);
    if (l == 0) wsum[w] = accsum;
    __syncthreads();
    if (t == 0) partials[b] = wsum[0] + wsum[1] + wsum[2] + wsum[3];
}

__global__ __launch_bounds__(256) void reduce_kernel(const float* __restrict__ bpp_part,
                                                     const float* __restrict__ reg_part,
                                                     float* __restrict__ out) {
    int t = threadIdx.x;
    float s1 = 0.f, s2 = 0.f;
    for (int i = t; i < NB_BPP; i += 256) s1 += bpp_part[i];
    for (int i = t; i < NTILES; i += 256) s2 += reg_part[i];
    __shared__ float r1[256], r2[256];
    r1[t] = s1; r2[t] = s2;
    __syncthreads();
    #pragma unroll
    for (int s = 128; s; s >>= 1) {
        if (t < s) { r1[t] += r1[t + s]; r2[t] += r2[t + s]; }
        __syncthreads();
    }
    if (t == 0) { out[0] = r1[0]; out[1] = r2[0]; }
}

extern "C" void kernel_launch(void* const* d_in, const int* in_sizes, int n_in,
                              void* d_out, int out_size, void* d_ws, size_t ws_size,
                              hipStream_t stream) {
    const int*   user_id    = (const int*)  d_in[0];
    const int*   pos_id     = (const int*)  d_in[1];
    const int*   neg_id     = (const int*)  d_in[2];
    const float* user_table = (const float*)d_in[3];
    const float* item_table = (const float*)d_in[4];
    const float* D          = (const float*)d_in[5];
    float* out = (float*)d_out;

    int*   sorted_id   = (int*)d_ws;                    // 4096
    int*   sorted_orig = sorted_id + NTOT;              // 4096
    float* bpp_part    = (float*)(sorted_orig + NTOT);  // 128
    float* reg_part    = bpp_part + NB_BPP;             // 2080

    combo_kernel<<<1 + NB_BPP, 1024, 0, stream>>>(user_id, pos_id, neg_id, user_table,
                                                  item_table, sorted_id, sorted_orig,
                                                  bpp_part);
    reg_kernel<<<NTILES, 256, 0, stream>>>(item_table, sorted_id, sorted_orig,
                                           D, reg_part);
    reduce_kernel<<<1, 256, 0, stream>>>(bpp_part, reg_part, out);
}

// Round 8
// 41.982 us; speedup vs baseline: 1.0269x; 1.0269x over previous
//
#include <hip/hip_runtime.h>
#include <math.h>

#define EMBED   64
#define BATCH   2048
#define NTOT    4096
#define NITEMS  10000
#define TILE    64
#define NT      64               // NTOT/TILE
#define NTILES  2080             // NT*(NT+1)/2, == 8*260
#define SROW    66               // bf16 LDS row stride: 33 dwords == 1 mod 32
#define NB_BPP  128              // 128 blocks x 16 waves = 2048 batch elems

typedef __attribute__((ext_vector_type(8))) short short8;
typedef __attribute__((ext_vector_type(4))) float f32x4;

__device__ __forceinline__ unsigned short f2bf(float f) {   // RNE fp32->bf16
    unsigned u = __float_as_uint(f);
    return (unsigned short)((u + 0x7FFFu + ((u >> 16) & 1u)) >> 16);
}

// block 0: counting sort of (id, orig) keys; blocks 1..128: bpp partials.
__global__ __launch_bounds__(1024) void combo_kernel(
    const int* __restrict__ user_id, const int* __restrict__ pos_id,
    const int* __restrict__ neg_id, const float* __restrict__ user_table,
    const float* __restrict__ item_table,
    int* __restrict__ sorted_id, int* __restrict__ sorted_orig,
    float* __restrict__ bpp_part)
{
    int blk = blockIdx.x, t = threadIdx.x;
    if (blk == 0) {
        __shared__ int hist[NITEMS];
        __shared__ unsigned key2[NTOT];
        __shared__ int wtot[16];
        for (int i = t; i < NITEMS; i += 1024) hist[i] = 0;
        __syncthreads();
        for (int i = t; i < NTOT; i += 1024) {
            int id = (i < BATCH) ? pos_id[i] : neg_id[i - BATCH];
            atomicAdd(&hist[id], 1);
        }
        __syncthreads();
        // exclusive scan over 10000 bins: 10 bins/thread, wave-shfl scan
        int b0 = t * 10, bend = min(b0 + 10, NITEMS);
        int s = 0;
        for (int b = b0; b < bend; ++b) s += hist[b];
        int lane = t & 63, wid = t >> 6;
        int v = s;
        #pragma unroll
        for (int off = 1; off < 64; off <<= 1) {
            int y = __shfl_up(v, off, 64);
            if (lane >= off) v += y;
        }
        if (lane == 63) wtot[wid] = v;
        __syncthreads();
        if (t == 0) {
            int run = 0;
            #pragma unroll
            for (int w = 0; w < 16; ++w) { int c = wtot[w]; wtot[w] = run; run += c; }
        }
        __syncthreads();
        int running = v - s + wtot[wid];   // exclusive prefix for this thread's bins
        for (int b = b0; b < bend; ++b) { int c = hist[b]; hist[b] = running; running += c; }
        __syncthreads();
        // scatter (atomic within bin), canonicalize equal-id runs by orig pos
        for (int i = t; i < NTOT; i += 1024) {
            int id = (i < BATCH) ? pos_id[i] : neg_id[i - BATCH];
            int pos = atomicAdd(&hist[id], 1);
            key2[pos] = ((unsigned)id << 12) | (unsigned)i;
        }
        __syncthreads();
        for (int p = 0; p < 12; ++p) {          // odd-even; run length <=12 whp
            int start = p & 1;
            for (int q = t; q < NTOT / 2; q += 1024) {
                int a = 2 * q + start;
                if (a + 1 < NTOT) {
                    unsigned x = key2[a], y = key2[a + 1];
                    if (x > y) { key2[a] = y; key2[a + 1] = x; }
                }
            }
            __syncthreads();
        }
        for (int i = t; i < NTOT; i += 1024) {
            sorted_id[i]   = (int)(key2[i] >> 12);
            sorted_orig[i] = (int)(key2[i] & 4095u);
        }
    } else {
        // bpp: 16 waves, one batch element per wave
        int b    = (blk - 1) * 16 + (t >> 6);
        int lane = t & 63;
        float u = user_table[user_id[b] * EMBED + lane];
        float p = item_table[pos_id[b]  * EMBED + lane];
        float n = item_table[neg_id[b]  * EMBED + lane];
        float dp = u * p, dn = u * n;
        #pragma unroll
        for (int off = 32; off; off >>= 1) {
            dp += __shfl_xor(dp, off, 64);
            dn += __shfl_xor(dn, off, 64);
        }
        float x = dn - dp;
        float sp = fmaxf(x, 0.f) + log1pf(expf(-fabsf(x)));
        __shared__ float red[16];
        if (lane == 0) red[t >> 6] = sp;
        __syncthreads();
        if (t == 0) {
            float ssum = 0.f;
            #pragma unroll
            for (int w = 0; w < 16; ++w) ssum += red[w];
            bpp_part[blk - 1] = ssum;
        }
    }
}

// One block per upper-tri 64x64 tile: MFMA dot tile + masked D-gather.
// Gather addresses computed from per-thread global reads of the (L2-hot)
// sorted arrays -> D-gathers issue before the LDS barrier and stay in
// flight across staging + MFMA. Row norms folded into staging.
__global__ __launch_bounds__(256) void reg_kernel(
    const float* __restrict__ item_table,
    const int* __restrict__ sorted_id, const int* __restrict__ sorted_orig,
    const float* __restrict__ D,
    float* __restrict__ partials)
{
    __shared__ unsigned short sa[TILE][SROW];
    __shared__ unsigned short sb[TILE][SROW];
    __shared__ float sqi[TILE], sqj[TILE];
    __shared__ float wsum[4];

    // XCD-aware swizzle: 2080 = 8 * 260 exactly -> bijective
    int bs = blockIdx.x;
    int b  = (bs & 7) * (NTILES / 8) + (bs >> 3);
    int tI = 0, rem = b;
    while (rem >= NT - tI) { rem -= NT - tI; ++tI; }
    int tJ = tI + rem;

    int t = threadIdx.x;
    int w = t >> 6, l = t & 63;
    int i_base = w * 16 + (l >> 4) * 4;

    // (A) per-thread sorted-array reads (L2-hot, broadcast/coalesced)
    int my_idi[4], my_ogi[4], my_idj[4], my_ogj[4];
    {
        int gI = tI * TILE + i_base;
        #pragma unroll
        for (int rr = 0; rr < 4; ++rr) {
            my_idi[rr] = sorted_id[gI + rr];
            my_ogi[rr] = sorted_orig[gI + rr];
        }
        #pragma unroll
        for (int cb = 0; cb < 4; ++cb) {
            int gJ = tJ * TILE + cb * 16 + (l & 15);
            my_idj[cb] = sorted_id[gJ];
            my_ogj[cb] = sorted_orig[gJ];
        }
    }

    // (B) staging loads into registers
    int r = t >> 2, c = t & 3;    // staging: row 0..63, 16-float chunk 0..3
    int idI = sorted_id[tI * TILE + r];
    int idJ = sorted_id[tJ * TILE + r];
    const float4* srcI = (const float4*)&item_table[idI * EMBED + c * 16];
    const float4* srcJ = (const float4*)&item_table[idJ * EMBED + c * 16];
    float4 aI[4], aJ[4];
    #pragma unroll
    for (int k = 0; k < 4; ++k) { aI[k] = srcI[k]; aJ[k] = srcJ[k]; }

    // (C) addresses + issue all 16 D-gathers (independent of LDS/barrier)
    float dg[16];
    #pragma unroll
    for (int cb = 0; cb < 4; ++cb) {
        int idb = my_idj[cb], ob = my_ogj[cb];
        int idbN = idb * NITEMS;
        #pragma unroll
        for (int rr = 0; rr < 4; ++rr) {
            bool fwd = my_ogi[rr] < ob;
            int addr = fwd ? (my_idi[rr] * NITEMS + idb) : (idbN + my_idi[rr]);
            dg[cb * 4 + rr] = D[addr];
        }
    }

    // (D) convert to bf16, write LDS, fold row-norm partials
    {
        float npI = 0.f, npJ = 0.f;
        #pragma unroll
        for (int k = 0; k < 4; ++k) {
            float4 vI = aI[k], vJ = aJ[k];
            npI = fmaf(vI.x, vI.x, fmaf(vI.y, vI.y, fmaf(vI.z, vI.z, fmaf(vI.w, vI.w, npI))));
            npJ = fmaf(vJ.x, vJ.x, fmaf(vJ.y, vJ.y, fmaf(vJ.z, vJ.z, fmaf(vJ.w, vJ.w, npJ))));
            ushort4 sI = { f2bf(vI.x), f2bf(vI.y), f2bf(vI.z), f2bf(vI.w) };
            ushort4 sJ = { f2bf(vJ.x), f2bf(vJ.y), f2bf(vJ.z), f2bf(vJ.w) };
            *(ushort4*)&sa[r][c * 16 + k * 4] = sI;
            *(ushort4*)&sb[r][c * 16 + k * 4] = sJ;
        }
        npI += __shfl_xor(npI, 1, 64); npI += __shfl_xor(npI, 2, 64);
        npJ += __shfl_xor(npJ, 1, 64); npJ += __shfl_xor(npJ, 2, 64);
        if (c == 0) { sqi[r] = npI; sqj[r] = npJ; }
    }
    __syncthreads();

    // MFMA dot tile. Wave w owns rows [w*16,w*16+16) x 64 cols; K=64 in 2.
    int arow = w * 16 + (l & 15);
    int kb   = (l >> 4) * 8;
    f32x4 acc[4];
    #pragma unroll
    for (int cb = 0; cb < 4; ++cb) acc[cb] = (f32x4){0.f, 0.f, 0.f, 0.f};
    #pragma unroll
    for (int s = 0; s < 2; ++s) {
        short8 af = *(const short8*)&sa[arow][s * 32 + kb];
        #pragma unroll
        for (int cb = 0; cb < 4; ++cb) {
            short8 bf = *(const short8*)&sb[cb * 16 + (l & 15)][s * 32 + kb];
            acc[cb] = __builtin_amdgcn_mfma_f32_16x16x32_bf16(af, bf, acc[cb], 0, 0, 0);
        }
    }

    // epilogue: distances, mask, fma with gathered D.
    // C/D map col=lane&15, row=(lane>>4)*4+reg (m89-verified).
    bool offdiag = (tI != tJ);   // wave-uniform
    float accsum = 0.f;
    #pragma unroll
    for (int cb = 0; cb < 4; ++cb) {
        int j_loc = cb * 16 + (l & 15);
        float sqb = sqj[j_loc];
        #pragma unroll
        for (int rr = 0; rr < 4; ++rr) {
            int i_loc = i_base + rr;
            float d2 = sqi[i_loc] + sqb - 2.f * acc[cb][rr];
            bool m = (d2 > 0.f) && (offdiag || (i_loc < j_loc));
            accsum = m ? fmaf(dg[cb * 4 + rr], sqrtf(d2), accsum) : accsum;
        }
    }

    // wave shfl-reduce, then block sum via 4-entry LDS
    #pragma unroll
    for (int off = 32; off; off >>= 1) accsum += __shfl_xor(accsum, off, 64);
    if (l == 0) wsum[w] = accsum;
    __syncthreads();
    if (t == 0) partials[b] = wsum[0] + wsum[1] + wsum[2] + wsum[3];
}

__global__ __launch_bounds__(256) void reduce_kernel(const float* __restrict__ bpp_part,
                                                     const float* __restrict__ reg_part,
                                                     float* __restrict__ out) {
    int t = threadIdx.x;
    float s1 = 0.f, s2 = 0.f;
    for (int i = t; i < NB_BPP; i += 256) s1 += bpp_part[i];
    for (int i = t; i < NTILES; i += 256) s2 += reg_part[i];
    __shared__ float r1[256], r2[256];
    r1[t] = s1; r2[t] = s2;
    __syncthreads();
    #pragma unroll
    for (int s = 128; s; s >>= 1) {
        if (t < s) { r1[t] += r1[t + s]; r2[t] += r2[t + s]; }
        __syncthreads();
    }
    if (t == 0) { out[0] = r1[0]; out[1] = r2[0]; }
}

extern "C" void kernel_launch(void* const* d_in, const int* in_sizes, int n_in,
                              void* d_out, int out_size, void* d_ws, size_t ws_size,
                              hipStream_t stream) {
    const int*   user_id    = (const int*)  d_in[0];
    const int*   pos_id     = (const int*)  d_in[1];
    const int*   neg_id     = (const int*)  d_in[2];
    const float* user_table = (const float*)d_in[3];
    const float* item_table = (const float*)d_in[4];
    const float* D          = (const float*)d_in[5];
    float* out = (float*)d_out;

    int*   sorted_id   = (int*)d_ws;                    // 4096
    int*   sorted_orig = sorted_id + NTOT;              // 4096
    float* bpp_part    = (float*)(sorted_orig + NTOT);  // 128
    float* reg_part    = bpp_part + NB_BPP;             // 2080

    combo_kernel<<<1 + NB_BPP, 1024, 0, stream>>>(user_id, pos_id, neg_id, user_table,
                                                  item_table, sorted_id, sorted_orig,
                                                  bpp_part);
    reg_kernel<<<NTILES, 256, 0, stream>>>(item_table, sorted_id, sorted_orig,
                                           D, reg_part);
    reduce_kernel<<<1, 256, 0, stream>>>(bpp_part, reg_part, out);
}